// Round 4
// baseline (250.532 us; speedup 1.0000x reference)
//
#include <hip/hip_runtime.h>

// StructuralLoss: windowed ZNCC loss, sigma=4 -> w=2 (4x4 box windows).
// Register-streaming, no LDS. Each thread owns 4 output columns, streams RY
// rows; 4-deep raw-row ring + 4-deep H ring in registers.
//
// HW model (R0-R3): gfx950 waves/SIMD = floor(256/VGPR). VGPR=108 -> 2
// waves/SIMD (19% occ). Kernel is HBM-latency-bound at that residency:
// R2 (load consumed ~20 instrs after issue) = 86us, VALUBusy 53%.
// R3 FAIL: prefetch reorder held t1/t2 partial sums across the loads ->
//   natural VGPR >128, cap spilled (WRITE 350KB), 108us. Lesson: prefetch
//   placement must not extend live ranges.
// R4: complete vertical sums FIRST (oldest ring slot fully consumed, no
// partials), THEN issue loads for row r+3 into the freed slot, THEN
// mu/c/H/emit (~200 VALU instrs before next-step use). Same latency cover
// as R3's intent, zero extra live state. Keep validated rsq epilogue +
// EDGEY specialization (absmax 0.0 in R3), RY=32.

#define HH 4096
#define WW 4096
constexpr int RY = 32;            // output rows per block tile
constexpr float EPf = 1e-20f;

__device__ __forceinline__ float4 zero4() { return make_float4(0.f, 0.f, 0.f, 0.f); }

struct ThreadState {
    // raw row rings: [slot][12 cols]  cols j0-4 .. j0+7 ; slot = row & 3
    float A[4][12];
    float B[4][12];
    // H rings: [slot][4 output cols]
    float Hii[4][4], Hjj[4][4], Hij[4][4];
    float cmask[7];               // c-column validity (cols j0-1 .. j0+5)
    float acc;
};

template <int SLOT, bool EDGEY>
__device__ __forceinline__ void load_row(ThreadState& st,
                                         const float* __restrict__ i1,
                                         const float* __restrict__ i2,
                                         int t, int j0, bool okL, bool okR) {
    float4 a0, a1, a2, b0, b1, b2;
    if (!EDGEY || (t >= 0 && t < HH)) {           // compile-time true for interior
        const float* p1 = i1 + (long)t * WW + j0;
        const float* p2 = i2 + (long)t * WW + j0;
        a0 = okL ? *(const float4*)(p1 - 4) : zero4();
        a1 = *(const float4*)(p1);
        a2 = okR ? *(const float4*)(p1 + 4) : zero4();
        b0 = okL ? *(const float4*)(p2 - 4) : zero4();
        b1 = *(const float4*)(p2);
        b2 = okR ? *(const float4*)(p2 + 4) : zero4();
    } else {
        a0 = a1 = a2 = b0 = b1 = b2 = zero4();
    }
    st.A[SLOT][0] = a0.x; st.A[SLOT][1] = a0.y; st.A[SLOT][2]  = a0.z; st.A[SLOT][3]  = a0.w;
    st.A[SLOT][4] = a1.x; st.A[SLOT][5] = a1.y; st.A[SLOT][6]  = a1.z; st.A[SLOT][7]  = a1.w;
    st.A[SLOT][8] = a2.x; st.A[SLOT][9] = a2.y; st.A[SLOT][10] = a2.z; st.A[SLOT][11] = a2.w;
    st.B[SLOT][0] = b0.x; st.B[SLOT][1] = b0.y; st.B[SLOT][2]  = b0.z; st.B[SLOT][3]  = b0.w;
    st.B[SLOT][4] = b1.x; st.B[SLOT][5] = b1.y; st.B[SLOT][6]  = b1.z; st.B[SLOT][7]  = b1.w;
    st.B[SLOT][8] = b2.x; st.B[SLOT][9] = b2.y; st.B[SLOT][10] = b2.z; st.B[SLOT][11] = b2.w;
}

template <int K, bool EDGEY, bool DOLOAD>
__device__ __forceinline__ void step(ThreadState& st,
                                     const float* __restrict__ i1,
                                     const float* __restrict__ i2,
                                     int rrb, int y0, int j0, bool okL, bool okR) {
    const int rr = rrb + K;          // iteration index 0..RY+2
    const int r  = y0 - 1 + rr;      // c-row produced this iteration
    // ring phase (y0 % 4 == 0, slot = row & 3):
    constexpr int SOLD = (K + 2) & 3;   // row r-1 (oldest; freed by phase A)
    constexpr int SC   = (K + 3) & 3;   // row r   (center)
    constexpr int SB   =  K;            // row r+1
    constexpr int SD   = (K + 1) & 3;   // row r+2

    // phase A: complete vertical 4-sums (rows r-1..r+2) -- fully consumes
    // the oldest slot; nothing partial survives past the load below.
    float vs1[12], vs2[12];
#pragma unroll
    for (int m = 0; m < 12; ++m) {
        vs1[m] = (st.A[SOLD][m] + st.A[SC][m]) + (st.A[SB][m] + st.A[SD][m]);
        vs2[m] = (st.B[SOLD][m] + st.B[SC][m]) + (st.B[SB][m] + st.B[SD][m]);
    }

    // phase B: prefetch row r+3 into the freed slot. Results are first
    // needed by the NEXT step's phase A, ~200 VALU instrs from here.
    if (DOLOAD)
        load_row<SOLD, EDGEY>(st, i1, i2, r + 3, j0, okL, okR);

    // phase C: mu, centered values, products, emit (ring use: SC only).
    const float rmask = (!EDGEY) ? 1.f : ((r >= 0 && r < HH) ? 1.f : 0.f);

    float c1[7], c2[7];
#pragma unroll
    for (int m = 0; m < 7; ++m) {
        float mu1 = (vs1[m + 2] + vs1[m + 3] + vs1[m + 4] + vs1[m + 5]) * 0.0625f;
        float mu2 = (vs2[m + 2] + vs2[m + 3] + vs2[m + 4] + vs2[m + 5]) * 0.0625f;
        float msk = EDGEY ? (rmask * st.cmask[m]) : st.cmask[m];
        c1[m] = (st.A[SC][m + 3] - mu1) * msk;
        c2[m] = (st.B[SC][m + 3] - mu2) * msk;
    }

    // horizontal 4-sums of products for the 4 output columns -> H ring slot K
#pragma unroll
    for (int q = 0; q < 4; ++q) {
        float hii = 0.f, hjj = 0.f, hij = 0.f;
#pragma unroll
        for (int s = 0; s < 4; ++s) {
            float a = c1[q + s], b = c2[q + s];
            hii += a * a;
            hjj += b * b;
            hij += a * b;
        }
        st.Hii[K][q] = hii; st.Hjj[K][q] = hjj; st.Hij[K][q] = hij;
    }

    // emit output row i = r-2 once H ring holds c-rows i-1..i+2
    if (rr >= 3 && rr <= RY + 2) {     // wave-uniform
#pragma unroll
        for (int q = 0; q < 4; ++q) {
            float sii = st.Hii[0][q] + st.Hii[1][q] + st.Hii[2][q] + st.Hii[3][q];
            float sjj = st.Hjj[0][q] + st.Hjj[1][q] + st.Hjj[2][q] + st.Hjj[3][q];
            float sij = st.Hij[0][q] + st.Hij[1][q] + st.Hij[2][q] + st.Hij[3][q];
            sii = fmaxf(sii, EPf);
            sjj = fmaxf(sjj, EPf);
            float pr = fmaxf(sii * sjj, 1e-35f);   // guard denormal flush -> rsq(0)=inf
            float L = sij * __builtin_amdgcn_rsqf(pr);
            L = fmaxf(L, -1.f);
            st.acc += 1.f - L;
        }
    }
}

template <bool EDGEY>
__device__ __forceinline__ float run_tile(const float* __restrict__ img1,
                                          const float* __restrict__ img2,
                                          int y0, int j0, bool okL, bool okR) {
    ThreadState st;
    st.acc = 0.f;
#pragma unroll
    for (int m = 0; m < 7; ++m) {
        int cc = j0 - 1 + m;
        st.cmask[m] = (cc >= 0 && cc < WW) ? 1.f : 0.f;
    }

    // prime ring: rows y0-2..y0+1 (slot = row & 3)
    load_row<0, EDGEY>(st, img1, img2, y0,     j0, okL, okR);
    load_row<1, EDGEY>(st, img1, img2, y0 + 1, j0, okL, okR);
    load_row<2, EDGEY>(st, img1, img2, y0 - 2, j0, okL, okR);
    load_row<3, EDGEY>(st, img1, img2, y0 - 1, j0, okL, okR);

    // steps rr = 0..RY+2 (c-rows y0-1..y0+RY+1); step rr prefetches row
    // r+3 = y0+2+rr, needed through rr = RY+1 (loads row y0+RY+3).
    for (int o = 0; o < RY / 4; ++o) {
        const int rrb = o * 4;
        step<0, EDGEY, true>(st, img1, img2, rrb, y0, j0, okL, okR);
        step<1, EDGEY, true>(st, img1, img2, rrb, y0, j0, okL, okR);
        step<2, EDGEY, true>(st, img1, img2, rrb, y0, j0, okL, okR);
        step<3, EDGEY, true>(st, img1, img2, rrb, y0, j0, okL, okR);
    }
    // tail: rr = RY, RY+1 (with load), RY+2 (no load)
    step<0, EDGEY, true >(st, img1, img2, RY, y0, j0, okL, okR);
    step<1, EDGEY, true >(st, img1, img2, RY, y0, j0, okL, okR);
    step<2, EDGEY, false>(st, img1, img2, RY, y0, j0, okL, okR);

    return st.acc;
}

__global__ __launch_bounds__(256, 2) void xcorr_loss_kernel(
    const float* __restrict__ img1, const float* __restrict__ img2,
    double* __restrict__ ws) {
    const int tcol = blockIdx.x * blockDim.x + threadIdx.x;  // thread col-group
    const int j0   = tcol * 4;
    const int y0   = blockIdx.y * RY;
    const bool okL = (j0 - 4) >= 0;
    const bool okR = (j0 + 7) < WW;

    float acc;
    if (blockIdx.y == 0 || blockIdx.y == gridDim.y - 1)
        acc = run_tile<true >(img1, img2, y0, j0, okL, okR);
    else
        acc = run_tile<false>(img1, img2, y0, j0, okL, okR);

    // wave (64-lane) reduction -> LDS -> one double atomic per block
    float wsum = acc;
#pragma unroll
    for (int off = 32; off > 0; off >>= 1)
        wsum += __shfl_down(wsum, off, 64);

    __shared__ float wpart[4];
    const int wid = threadIdx.x >> 6;
    if ((threadIdx.x & 63) == 0) wpart[wid] = wsum;
    __syncthreads();
    if (threadIdx.x == 0) {
        float bsum = wpart[0] + wpart[1] + wpart[2] + wpart[3];
        atomicAdd(ws, (double)bsum);
    }
}

__global__ void finalize_kernel(const double* __restrict__ ws, float* __restrict__ out) {
    double mean = ws[0] / ((double)HH * (double)WW);
    out[0] = (float)mean;
    out[1] = (float)mean;
}

extern "C" void kernel_launch(void* const* d_in, const int* in_sizes, int n_in,
                              void* d_out, int out_size, void* d_ws, size_t ws_size,
                              hipStream_t stream) {
    const float* img1 = (const float*)d_in[0];  // outputs
    const float* img2 = (const float*)d_in[1];  // labels
    double* ws = (double*)d_ws;

    hipMemsetAsync(d_ws, 0, sizeof(double), stream);

    dim3 grid(WW / (256 * 4), HH / RY);   // (4, 128) = 512 blocks
    xcorr_loss_kernel<<<grid, dim3(256), 0, stream>>>(img1, img2, ws);
    finalize_kernel<<<1, 1, 0, stream>>>(ws, (float*)d_out);
}

// Round 5
// 205.332 us; speedup vs baseline: 1.2201x; 1.2201x over previous
//
#include <hip/hip_runtime.h>

// StructuralLoss: windowed ZNCC loss, sigma=4 -> w=2 (4x4 box windows).
//
// HW model (R0-R4): VGPR=108 -> 2 waves/SIMD; kernel latency-bound.
// R3/R4 PROVED: keeping global loads in flight across the compute phase of
// the register-ring structure exceeds 128 VGPR -> spill (WRITE 350KB/1.5MB).
// The 96-reg raw ring + latency hiding + <=128 VGPR are mutually exclusive.
//
// R5: raw-row ring moves to LDS (5 slots x 2 imgs x 1040 cols, zero-filled
// halo). Per step: (1) issue 2-3 float4 global loads for row r+3 into a
// 12-reg staging buffer (no wait); (2) compute entirely from LDS
// (24 ds_read_b128 + vs/mu/c/H/emit, independent of in-flight loads -> full
// step of latency cover); (3) waitcnt + ds_write + ONE barrier. In-flight
// state is 12 regs by construction -- the R3/R4 spill cannot recur.
// Halo zero-fill at stage time also removes the okL/okR cndmasks.
// Keep validated: rsq epilogue, EDGEY specialization, block-level atomic.

#define HH 4096
#define WW 4096
constexpr int RY    = 16;          // output rows per block tile
constexpr int BX    = 1024;        // output cols per block (256 thr x 4)
constexpr int LROW  = 1040;        // floats per image per slot (1032 used + 8 pad)
constexpr int SLOTF = 2 * LROW;    // floats per row-slot (img1 then img2)
constexpr int NSLOT = 5;           // rows r-1..r+2 live + r+3 staging
constexpr float EPf = 1e-20f;

static_assert(RY % 4 == 0, "RY multiple of 4");

__device__ __forceinline__ float4 zero4() { return make_float4(0.f, 0.f, 0.f, 0.f); }

// Staging: row segment cols [C0-4, C0+1028) per image = 258 float4 per image.
// Thread t owns chunks q = t, q = t+256, and (t<4) q = 512+t, where
// q < 258 -> img1 chunk q ; q >= 258 -> img2 chunk q-258.
struct StageBuf { float4 v0, v1, v2; };

template <bool EDGEY>
__device__ __forceinline__ void stage_issue(StageBuf& sb,
        const float* __restrict__ i1, const float* __restrict__ i2,
        int t, int C0, int tid) {
    sb.v0 = zero4(); sb.v1 = zero4(); sb.v2 = zero4();
    if (EDGEY && ((unsigned)t >= (unsigned)HH)) return;   // OOR row -> zeros
    const float* r1 = i1 + (long)t * WW;
    const float* r2 = i2 + (long)t * WW;
    {   // chunk q0 = tid (always img1)
        int g0 = C0 - 4 + 4 * tid;
        if ((unsigned)g0 < (unsigned)WW) sb.v0 = *(const float4*)(r1 + g0);
    }
    {   // chunk q1 = tid + 256
        int q = tid + 256;
        const float* base = (q >= 258) ? r2 : r1;
        int u  = (q >= 258) ? q - 258 : q;
        int g0 = C0 - 4 + 4 * u;
        if ((unsigned)g0 < (unsigned)WW) sb.v1 = *(const float4*)(base + g0);
    }
    if (tid < 4) {  // chunk q2 = 512 + tid (img2 u = 254..257)
        int g0 = C0 - 4 + 4 * (254 + tid);
        if ((unsigned)g0 < (unsigned)WW) sb.v2 = *(const float4*)(r2 + g0);
    }
}

__device__ __forceinline__ void stage_commit(float* slot, const StageBuf& sb, int tid) {
    *(float4*)(slot + 4 * tid) = sb.v0;
    int q   = tid + 256;
    int off = (q >= 258) ? (LROW + 4 * (q - 258)) : 4 * q;
    *(float4*)(slot + off) = sb.v1;
    if (tid < 4)
        *(float4*)(slot + LROW + 4 * (254 + tid)) = sb.v2;
}

struct TS {
    float Hii[4][4], Hjj[4][4], Hij[4][4];  // H ring: [slot rr&3][4 output cols]
    float cmask[7];                         // c-column validity (cols j0-1..j0+5)
    float acc;
};

template <int K, bool EDGEY, bool DOLOAD>
__device__ __forceinline__ void step(float* __restrict__ lds, TS& st,
        const float* __restrict__ i1, const float* __restrict__ i2,
        int rr, int y0, int C0, int tid) {
    const int r = y0 - 1 + rr;        // c-row produced this iteration

    // (1) issue stage loads for row r+3 (results needed next step via LDS)
    StageBuf sb;
    if (DOLOAD) stage_issue<EDGEY>(sb, i1, i2, r + 3, C0, tid);

    // (2) compute from LDS rows r-1..r+2 (slot = (row+10) % 5, row >= -3)
    const float* p0 = lds + ((r + 9)  % NSLOT) * SLOTF;   // row r-1
    const float* p1 = lds + ((r + 10) % NSLOT) * SLOTF;   // row r (center)
    const float* p2 = lds + ((r + 11) % NSLOT) * SLOTF;   // row r+1
    const float* p3 = lds + ((r + 12) % NSLOT) * SLOTF;   // row r+2
    const int lb = 4 * tid;           // local col of j0-4 within the slot

    float vs1[12], vs2[12], cA[12], cB[12];
#pragma unroll
    for (int g = 0; g < 3; ++g) {
        float4 a0 = *(const float4*)(p0 + lb + 4 * g);
        float4 a1 = *(const float4*)(p1 + lb + 4 * g);
        float4 a2 = *(const float4*)(p2 + lb + 4 * g);
        float4 a3 = *(const float4*)(p3 + lb + 4 * g);
        vs1[4*g+0] = (a0.x + a1.x) + (a2.x + a3.x);  cA[4*g+0] = a1.x;
        vs1[4*g+1] = (a0.y + a1.y) + (a2.y + a3.y);  cA[4*g+1] = a1.y;
        vs1[4*g+2] = (a0.z + a1.z) + (a2.z + a3.z);  cA[4*g+2] = a1.z;
        vs1[4*g+3] = (a0.w + a1.w) + (a2.w + a3.w);  cA[4*g+3] = a1.w;
        float4 b0 = *(const float4*)(p0 + LROW + lb + 4 * g);
        float4 b1 = *(const float4*)(p1 + LROW + lb + 4 * g);
        float4 b2 = *(const float4*)(p2 + LROW + lb + 4 * g);
        float4 b3 = *(const float4*)(p3 + LROW + lb + 4 * g);
        vs2[4*g+0] = (b0.x + b1.x) + (b2.x + b3.x);  cB[4*g+0] = b1.x;
        vs2[4*g+1] = (b0.y + b1.y) + (b2.y + b3.y);  cB[4*g+1] = b1.y;
        vs2[4*g+2] = (b0.z + b1.z) + (b2.z + b3.z);  cB[4*g+2] = b1.z;
        vs2[4*g+3] = (b0.w + b1.w) + (b2.w + b3.w);  cB[4*g+3] = b1.w;
    }

    const float rmask = (!EDGEY) ? 1.f : (((unsigned)r < (unsigned)HH) ? 1.f : 0.f);

    // centered values at 7 c-columns (global col j0-1+m <-> cA[3+m])
    float c1[7], c2[7];
#pragma unroll
    for (int m = 0; m < 7; ++m) {
        float mu1 = (vs1[m + 2] + vs1[m + 3] + vs1[m + 4] + vs1[m + 5]) * 0.0625f;
        float mu2 = (vs2[m + 2] + vs2[m + 3] + vs2[m + 4] + vs2[m + 5]) * 0.0625f;
        float msk = EDGEY ? (rmask * st.cmask[m]) : st.cmask[m];
        c1[m] = (cA[m + 3] - mu1) * msk;
        c2[m] = (cB[m + 3] - mu2) * msk;
    }

    // horizontal 4-sums of products for the 4 output columns -> H ring slot K
#pragma unroll
    for (int q = 0; q < 4; ++q) {
        float hii = 0.f, hjj = 0.f, hij = 0.f;
#pragma unroll
        for (int s = 0; s < 4; ++s) {
            float a = c1[q + s], b = c2[q + s];
            hii += a * a;
            hjj += b * b;
            hij += a * b;
        }
        st.Hii[K][q] = hii; st.Hjj[K][q] = hjj; st.Hij[K][q] = hij;
    }

    // emit output row i = r-2 once H ring holds c-rows i-1..i+2
    if (rr >= 3) {                     // wave-uniform (rr <= RY+2 by loop bounds)
#pragma unroll
        for (int q = 0; q < 4; ++q) {
            float sii = st.Hii[0][q] + st.Hii[1][q] + st.Hii[2][q] + st.Hii[3][q];
            float sjj = st.Hjj[0][q] + st.Hjj[1][q] + st.Hjj[2][q] + st.Hjj[3][q];
            float sij = st.Hij[0][q] + st.Hij[1][q] + st.Hij[2][q] + st.Hij[3][q];
            sii = fmaxf(sii, EPf);
            sjj = fmaxf(sjj, EPf);
            float pr = fmaxf(sii * sjj, 1e-35f);   // guard denormal -> rsq(0)=inf
            float L = sij * __builtin_amdgcn_rsqf(pr);
            L = fmaxf(L, -1.f);
            st.acc += 1.f - L;
        }
    }

    // (3) commit stage to the freed slot (its readers finished last step,
    // protected by the previous barrier), then one barrier: orders our
    // writes before next step's reads AND our reads before next step's writes.
    if (DOLOAD)
        stage_commit(lds + ((r + 13) % NSLOT) * SLOTF, sb, tid);
    __syncthreads();
}

template <bool EDGEY>
__device__ __forceinline__ float run_tile(float* __restrict__ lds,
        const float* __restrict__ img1, const float* __restrict__ img2,
        int y0, int C0, int tid) {
    TS st;
    st.acc = 0.f;
    const int j0 = C0 + 4 * tid;
#pragma unroll
    for (int m = 0; m < 7; ++m) {
        int cc = j0 - 1 + m;
        st.cmask[m] = (cc >= 0 && cc < WW) ? 1.f : 0.f;
    }

    // prologue: stage rows y0-2..y0+1 (2 at a time; writes to distinct slots)
    {
        StageBuf s0, s1;
        stage_issue<EDGEY>(s0, img1, img2, y0 - 2, C0, tid);
        stage_issue<EDGEY>(s1, img1, img2, y0 - 1, C0, tid);
        stage_commit(lds + ((y0 + 8) % NSLOT) * SLOTF, s0, tid);
        stage_commit(lds + ((y0 + 9) % NSLOT) * SLOTF, s1, tid);
        stage_issue<EDGEY>(s0, img1, img2, y0,     C0, tid);
        stage_issue<EDGEY>(s1, img1, img2, y0 + 1, C0, tid);
        stage_commit(lds + ((y0 + 10) % NSLOT) * SLOTF, s0, tid);
        stage_commit(lds + ((y0 + 11) % NSLOT) * SLOTF, s1, tid);
    }
    __syncthreads();

    // steps rr = 0..RY+2 (19); step rr stages row y0+2+rr for rr <= RY+1
    for (int o = 0; o < RY / 4; ++o) {
        const int rrb = o * 4;
        step<0, EDGEY, true>(lds, st, img1, img2, rrb + 0, y0, C0, tid);
        step<1, EDGEY, true>(lds, st, img1, img2, rrb + 1, y0, C0, tid);
        step<2, EDGEY, true>(lds, st, img1, img2, rrb + 2, y0, C0, tid);
        step<3, EDGEY, true>(lds, st, img1, img2, rrb + 3, y0, C0, tid);
    }
    step<0, EDGEY, true >(lds, st, img1, img2, RY + 0, y0, C0, tid);
    step<1, EDGEY, true >(lds, st, img1, img2, RY + 1, y0, C0, tid);
    step<2, EDGEY, false>(lds, st, img1, img2, RY + 2, y0, C0, tid);

    return st.acc;
}

__global__ __launch_bounds__(256) void xcorr_loss_kernel(
    const float* __restrict__ img1, const float* __restrict__ img2,
    double* __restrict__ ws) {
    __shared__ float lds[NSLOT * SLOTF];   // 41.6 KB
    __shared__ float wpart[4];

    const int tid = threadIdx.x;
    const int C0  = blockIdx.x * BX;
    const int y0  = blockIdx.y * RY;

    float acc;
    if (blockIdx.y == 0 || blockIdx.y == gridDim.y - 1)
        acc = run_tile<true >(lds, img1, img2, y0, C0, tid);
    else
        acc = run_tile<false>(lds, img1, img2, y0, C0, tid);

    // wave reduction -> LDS -> one double atomic per block
    float wsum = acc;
#pragma unroll
    for (int off = 32; off > 0; off >>= 1)
        wsum += __shfl_down(wsum, off, 64);

    const int wid = tid >> 6;
    if ((tid & 63) == 0) wpart[wid] = wsum;
    __syncthreads();
    if (tid == 0) {
        float bsum = wpart[0] + wpart[1] + wpart[2] + wpart[3];
        atomicAdd(ws, (double)bsum);
    }
}

__global__ void finalize_kernel(const double* __restrict__ ws, float* __restrict__ out) {
    double mean = ws[0] / ((double)HH * (double)WW);
    out[0] = (float)mean;
    out[1] = (float)mean;
}

extern "C" void kernel_launch(void* const* d_in, const int* in_sizes, int n_in,
                              void* d_out, int out_size, void* d_ws, size_t ws_size,
                              hipStream_t stream) {
    const float* img1 = (const float*)d_in[0];  // outputs
    const float* img2 = (const float*)d_in[1];  // labels
    double* ws = (double*)d_ws;

    hipMemsetAsync(d_ws, 0, sizeof(double), stream);

    dim3 grid(WW / BX, HH / RY);   // (4, 256) = 1024 blocks
    xcorr_loss_kernel<<<grid, dim3(256), 0, stream>>>(img1, img2, ws);
    finalize_kernel<<<1, 1, 0, stream>>>(ws, (float*)d_out);
}

// Round 6
// 203.255 us; speedup vs baseline: 1.2326x; 1.0102x over previous
//
#include <hip/hip_runtime.h>

// StructuralLoss: windowed ZNCC loss, sigma=4 -> w=2 (4x4 box windows).
//
// R5 post-mortem (counters): SQ_LDS_BANK_CONFLICT 2.49e7 ~= 12 x (#b128 LDS
// ops) -> counter measures inherent wave64 wide-op cycles, NOT bad banking.
// VALU 27% and LDS pipe ~28% both unsaturated -> the loss was the schedule:
// issue loads -> compute -> vmcnt-drain + commit + __syncthreads in the SAME
// step (zero latency cover, barrier-coupled), plus 4x vertical re-read of
// raw rows from LDS.
//
// R6 restructure ("exchange derived, not raw"):
//  - 2 output cols/thread; 6-deep raw ring in REGISTERS (24 regs; spill-safe)
//  - global loads issued 2 full steps before first use (~550+ cyc cover)
//  - LDS holds only per-c-row derived data needing horizontal halos:
//    vs (vertical 4-sums) + products (ii,jj,ij), double-buffered.
//    3 b128 writes + 5 b128 reads per step (vs R5's 26).
//  - custom lgkm-only barrier (s_waitcnt lgkmcnt(0); s_barrier): global loads
//    go to private regs only, so no vmcnt drain needed -> prefetch survives
//    the barrier (unlike __syncthreads).
//  - x-decomposition: 9 blocks x 504 owned cols, +-4 col pipeline halo,
//    ownership masks; image zero-padding falls out of predicated loads and
//    zeroed LDS boundary entries.
//  - keep validated: rsq epilogue, EDGEY specialization, block-level atomic.

#define HH 4096
#define WW 4096
constexpr int RY  = 32;            // output rows per block tile
constexpr int NST = RY + 4;        // 36 pipeline steps = 3 x 12 template phases
constexpr int BO  = 504;           // output cols owned per block
constexpr int NXB = 9;             // ceil(WW / BO)
constexpr float EPf = 1e-20f;

using F4 = float4;

// lgkm-only barrier: orders LDS writes/reads without draining global vmcnt.
__device__ __forceinline__ void sync_lds() {
    asm volatile("s_waitcnt lgkmcnt(0)\n\ts_barrier" ::: "memory");
}

struct Regs {
    float ra[6][2], rb[6][2];                   // raw ring: 6 rows x 2 cols x 2 imgs
    float pii0, pjj0, pij0, pii1, pjj1, pij1;   // products carry (c-row r-1)
    float Hii[4][2], Hjj[4][2], Hij[4][2];      // H ring (horiz sums per c-row)
    float m;                                    // column mask (image pad)
    bool  own;                                  // output-col ownership
    float acc;
};

template <bool EDGEY>
__device__ __forceinline__ void ld_row(float (&a)[2], float (&b)[2],
        const float* __restrict__ i1, const float* __restrict__ i2,
        int trow, int p0, bool okc) {
    bool ok = okc;
    if (EDGEY) ok = ok && ((unsigned)trow < (unsigned)HH);
    float2 va = make_float2(0.f, 0.f), vb = make_float2(0.f, 0.f);
    if (ok) {
        const unsigned off = (unsigned)trow * (unsigned)WW + (unsigned)p0;
        va = *(const float2*)(i1 + off);
        vb = *(const float2*)(i2 + off);
    }
    a[0] = va.x; a[1] = va.y; b[0] = vb.x; b[1] = vb.y;
}

// One pipeline step. rr = step index (runtime, wave-uniform), K = rr % 12.
// c-row r = y0-1+rr. Ring slot of row u is (u - y0 + 2) % 6.
template <int K, bool EDGEY>
__device__ __forceinline__ void step(Regs& R, int rr, int y0, int p0, bool okc,
        const float* __restrict__ i1, const float* __restrict__ i2,
        F4 (*__restrict__ vsL)[258], F4 (*__restrict__ plA)[258],
        F4 (*__restrict__ plB)[258], int tid) {
    constexpr int Sm1 = (K + 0) % 6;   // row r-1
    constexpr int S0  = (K + 1) % 6;   // row r (center)
    constexpr int Sp1 = (K + 2) % 6;   // row r+1
    constexpr int Sp2 = (K + 3) % 6;   // row r+2
    constexpr int Sld = (K + 5) % 6;   // load target: row r+4
    constexpr int HS  = K % 4;         // H ring slot for c-row r-1
    constexpr int BUF = K % 2;         // LDS double-buffer

    // vertical 4-sums for c-row r at own 2 cols (all register ring)
    float vs1_0 = (R.ra[Sm1][0] + R.ra[S0][0]) + (R.ra[Sp1][0] + R.ra[Sp2][0]);
    float vs1_1 = (R.ra[Sm1][1] + R.ra[S0][1]) + (R.ra[Sp1][1] + R.ra[Sp2][1]);
    float vs2_0 = (R.rb[Sm1][0] + R.rb[S0][0]) + (R.rb[Sp1][0] + R.rb[Sp2][0]);
    float vs2_1 = (R.rb[Sm1][1] + R.rb[S0][1]) + (R.rb[Sp1][1] + R.rb[Sp2][1]);

    vsL[BUF][tid + 1] = make_float4(vs1_0, vs1_1, vs2_0, vs2_1);
    plA[BUF][tid + 1] = make_float4(R.pii0, R.pjj0, R.pij0, 0.f);  // col p0
    plB[BUF][tid + 1] = make_float4(R.pii1, R.pjj1, R.pij1, 0.f);  // col p0+1

    // prefetch row r+4 = y0+3+rr into its ring slot (first used 2 steps later)
    if (rr <= RY)
        ld_row<EDGEY>(R.ra[Sld], R.rb[Sld], i1, i2, y0 + 3 + rr, p0, okc);

    sync_lds();

    const F4 vL  = vsL[BUF][tid];       // vs at cols p0-2, p0-1 (.y/.w used)
    const F4 vR  = vsL[BUF][tid + 2];   // vs at cols p0+2, p0+3
    const F4 hL  = plB[BUF][tid];       // products col p0-1
    const F4 hR0 = plA[BUF][tid + 2];   // products col p0+2
    const F4 hR1 = plB[BUF][tid + 2];   // products col p0+3

    // H for c-row r-1: H[o] = sum products cols [o-1, o+2]
    R.Hii[HS][0] = (hL.x + R.pii0) + (R.pii1 + hR0.x);
    R.Hjj[HS][0] = (hL.y + R.pjj0) + (R.pjj1 + hR0.y);
    R.Hij[HS][0] = (hL.z + R.pij0) + (R.pij1 + hR0.z);
    R.Hii[HS][1] = (R.pii0 + R.pii1) + (hR0.x + hR1.x);
    R.Hjj[HS][1] = (R.pjj0 + R.pjj1) + (hR0.y + hR1.y);
    R.Hij[HS][1] = (R.pij0 + R.pij1) + (hR0.z + hR1.z);

    // emit output row i = y0+rr-4 once H ring holds c-rows i-1..i+2
    if (rr >= 4) {
#pragma unroll
        for (int q = 0; q < 2; ++q) {
            float sii = (R.Hii[0][q] + R.Hii[1][q]) + (R.Hii[2][q] + R.Hii[3][q]);
            float sjj = (R.Hjj[0][q] + R.Hjj[1][q]) + (R.Hjj[2][q] + R.Hjj[3][q]);
            float sij = (R.Hij[0][q] + R.Hij[1][q]) + (R.Hij[2][q] + R.Hij[3][q]);
            sii = fmaxf(sii, EPf);
            sjj = fmaxf(sjj, EPf);
            float pr = fmaxf(sii * sjj, 1e-35f);
            float L  = sij * __builtin_amdgcn_rsqf(pr);
            L = fmaxf(L, -1.f);
            float v = 1.f - L;
            R.acc += R.own ? v : 0.f;
        }
    }

    // new products for c-row r -> carry. mu[c] = sum vs[c-1..c+2] / 16.
    float mu1_0 = ((vL.y + vs1_0) + (vs1_1 + vR.x)) * 0.0625f;
    float mu1_1 = ((vs1_0 + vs1_1) + (vR.x + vR.y)) * 0.0625f;
    float mu2_0 = ((vL.w + vs2_0) + (vs2_1 + vR.z)) * 0.0625f;
    float mu2_1 = ((vs2_0 + vs2_1) + (vR.z + vR.w)) * 0.0625f;
    float msk = R.m;
    if (EDGEY) {
        const int r = y0 - 1 + rr;
        msk *= ((unsigned)r < (unsigned)HH) ? 1.f : 0.f;
    }
    const float c1_0 = (R.ra[S0][0] - mu1_0) * msk;
    const float c1_1 = (R.ra[S0][1] - mu1_1) * msk;
    const float c2_0 = (R.rb[S0][0] - mu2_0) * msk;
    const float c2_1 = (R.rb[S0][1] - mu2_1) * msk;
    R.pii0 = c1_0 * c1_0; R.pjj0 = c2_0 * c2_0; R.pij0 = c1_0 * c2_0;
    R.pii1 = c1_1 * c1_1; R.pjj1 = c2_1 * c2_1; R.pij1 = c1_1 * c2_1;
}

template <bool EDGEY>
__device__ float run_tile(const float* __restrict__ i1, const float* __restrict__ i2,
        int y0, int X0, int tid,
        F4 (*vsL)[258], F4 (*plA)[258], F4 (*plB)[258]) {
    Regs R;
    const int p0 = X0 - 4 + 2 * tid;               // own cols p0, p0+1 (p0 even)
    const bool okc = ((unsigned)p0 < (unsigned)WW); // whole float2 in-image
    R.m   = okc ? 1.f : 0.f;
    R.own = (p0 >= X0) && (p0 < X0 + BO) && (p0 < WW);
    R.pii0 = R.pjj0 = R.pij0 = 0.f;
    R.pii1 = R.pjj1 = R.pij1 = 0.f;
    R.acc = 0.f;

    // zero the never-written LDS boundary entries (block-edge halos; for
    // block 0 these are the true zero-padding values)
    if (tid < 2) {
        const int e = tid ? 257 : 0;
        const F4 z = make_float4(0.f, 0.f, 0.f, 0.f);
        vsL[0][e] = z; vsL[1][e] = z;
        plA[0][e] = z; plA[1][e] = z;
        plB[0][e] = z; plB[1][e] = z;
    }

    // prime ring: rows y0-2 .. y0+2 -> slots 0..4 (slot 5 filled by step 0)
    ld_row<EDGEY>(R.ra[0], R.rb[0], i1, i2, y0 - 2, p0, okc);
    ld_row<EDGEY>(R.ra[1], R.rb[1], i1, i2, y0 - 1, p0, okc);
    ld_row<EDGEY>(R.ra[2], R.rb[2], i1, i2, y0,     p0, okc);
    ld_row<EDGEY>(R.ra[3], R.rb[3], i1, i2, y0 + 1, p0, okc);
    ld_row<EDGEY>(R.ra[4], R.rb[4], i1, i2, y0 + 2, p0, okc);

#pragma unroll 1
    for (int g = 0; g < 3; ++g) {
        const int rb = g * 12;
        step< 0, EDGEY>(R, rb +  0, y0, p0, okc, i1, i2, vsL, plA, plB, tid);
        step< 1, EDGEY>(R, rb +  1, y0, p0, okc, i1, i2, vsL, plA, plB, tid);
        step< 2, EDGEY>(R, rb +  2, y0, p0, okc, i1, i2, vsL, plA, plB, tid);
        step< 3, EDGEY>(R, rb +  3, y0, p0, okc, i1, i2, vsL, plA, plB, tid);
        step< 4, EDGEY>(R, rb +  4, y0, p0, okc, i1, i2, vsL, plA, plB, tid);
        step< 5, EDGEY>(R, rb +  5, y0, p0, okc, i1, i2, vsL, plA, plB, tid);
        step< 6, EDGEY>(R, rb +  6, y0, p0, okc, i1, i2, vsL, plA, plB, tid);
        step< 7, EDGEY>(R, rb +  7, y0, p0, okc, i1, i2, vsL, plA, plB, tid);
        step< 8, EDGEY>(R, rb +  8, y0, p0, okc, i1, i2, vsL, plA, plB, tid);
        step< 9, EDGEY>(R, rb +  9, y0, p0, okc, i1, i2, vsL, plA, plB, tid);
        step<10, EDGEY>(R, rb + 10, y0, p0, okc, i1, i2, vsL, plA, plB, tid);
        step<11, EDGEY>(R, rb + 11, y0, p0, okc, i1, i2, vsL, plA, plB, tid);
    }
    return R.acc;
}

__global__ __launch_bounds__(256) void xcorr_loss_kernel(
        const float* __restrict__ img1, const float* __restrict__ img2,
        double* __restrict__ ws) {
    __shared__ F4 vsL[2][258];
    __shared__ F4 plA[2][258];
    __shared__ F4 plB[2][258];
    __shared__ float wpart[4];

    const int tid = threadIdx.x;
    const int X0 = blockIdx.x * BO;
    const int y0 = blockIdx.y * RY;

    float acc;
    if (blockIdx.y == 0 || blockIdx.y == gridDim.y - 1)
        acc = run_tile<true >(img1, img2, y0, X0, tid, vsL, plA, plB);
    else
        acc = run_tile<false>(img1, img2, y0, X0, tid, vsL, plA, plB);

    // wave reduction -> LDS -> one double atomic per block
    float wsum = acc;
#pragma unroll
    for (int off = 32; off > 0; off >>= 1)
        wsum += __shfl_down(wsum, off, 64);
    const int wid = tid >> 6;
    if ((tid & 63) == 0) wpart[wid] = wsum;
    __syncthreads();
    if (tid == 0)
        atomicAdd(ws, (double)((wpart[0] + wpart[1]) + (wpart[2] + wpart[3])));
}

__global__ void finalize_kernel(const double* __restrict__ ws, float* __restrict__ out) {
    double mean = ws[0] / ((double)HH * (double)WW);
    out[0] = (float)mean;
    out[1] = (float)mean;
}

extern "C" void kernel_launch(void* const* d_in, const int* in_sizes, int n_in,
                              void* d_out, int out_size, void* d_ws, size_t ws_size,
                              hipStream_t stream) {
    const float* img1 = (const float*)d_in[0];  // outputs
    const float* img2 = (const float*)d_in[1];  // labels
    double* ws = (double*)d_ws;

    hipMemsetAsync(d_ws, 0, sizeof(double), stream);

    dim3 grid(NXB, HH / RY);   // (9, 128) = 1152 blocks
    xcorr_loss_kernel<<<grid, dim3(256), 0, stream>>>(img1, img2, ws);
    finalize_kernel<<<1, 1, 0, stream>>>(ws, (float*)d_out);
}

// Round 7
// 180.350 us; speedup vs baseline: 1.3891x; 1.1270x over previous
//
#include <hip/hip_runtime.h>

// StructuralLoss: windowed ZNCC, sigma=4 -> w=2 (4x4 box windows).
//
// Structure history: R2 (reg-ring, fat halo, no exchange) 86us / VALU 53%.
// R5/R6 (LDS exchange + per-step __syncthreads/lgkm-barrier) 140/101us --
// barrier around tiny steps couples 4 waves to every LDS+latency chain;
// VALUBusy sank to 24%. R3/R4: prefetch within the fat-halo structure
// spills (>128 VGPR). Conclusion: exchange must be BARRIER-FREE.
//
// R7: wave-local halo exchange via cross-lane shuffles (ds_bpermute; no
// barriers anywhere in the kernel).
//  - lane owns 2 cols; wave = 128 cols = 120 owned + 4 halo each side
//    (own-masked, ~7% redundant compute). 36 waves tile WW; waves never
//    communicate. Block = 4 independent waves.
//  - per-thread state: raw ring 4x2x2=16 + H ring 24 + masks/acc ~3
//    => ~75-95 VGPR natural, no spill possible; plain launch_bounds.
//  - per step: vs(ring) -> 6 shfl (vs halo) -> mu -> c -> 6 shfl (c halo)
//    -> halo products local (9 mul) -> H -> ring -> emit(rsq).
//  - loads for row r+3 issued right after vs frees the oldest slot
//    (one-full-step distance, only 8B/lane in flight).
//  - keep validated: rsq epilogue + clamp guards, EDGEY, block atomic.

#define HH 4096
#define WW 4096
constexpr int RY   = 32;             // output rows per block tile
constexpr int WOWN = 120;            // owned cols per wave
constexpr int WPB  = 4;              // waves per block
constexpr int BO   = WOWN * WPB;     // 480 owned cols per block
constexpr int NXB  = (WW + BO - 1) / BO;   // 9
constexpr float EPf = 1e-20f;

__device__ __forceinline__ float up1(float v) { return __shfl_up(v, 1, 64); }
__device__ __forceinline__ float dn1(float v) { return __shfl_down(v, 1, 64); }

struct Regs {
    float ra[4][2], rb[4][2];               // raw ring: 4 rows x 2 cols x 2 imgs
    float Hii[4][2], Hjj[4][2], Hij[4][2];  // H ring per c-row
    float mc;                               // col-pair validity (image pad)
    float ownf;                             // ownership mask for emit
    float acc;
};

template <int SLOT, bool EDGEY>
__device__ __forceinline__ void ld_row(Regs& R,
        const float* __restrict__ i1, const float* __restrict__ i2,
        int t, int p0) {
    bool ok = ((unsigned)p0 < (unsigned)WW);
    if (EDGEY) ok = ok && ((unsigned)t < (unsigned)HH);
    float2 va = make_float2(0.f, 0.f), vb = make_float2(0.f, 0.f);
    if (ok) {
        const size_t off = (size_t)t * WW + (unsigned)p0;
        va = *(const float2*)(i1 + off);
        vb = *(const float2*)(i2 + off);
    }
    R.ra[SLOT][0] = va.x; R.ra[SLOT][1] = va.y;
    R.rb[SLOT][0] = vb.x; R.rb[SLOT][1] = vb.y;
}

// Step rr (c-row r = y0-1+rr), K = rr & 3. Ring: row u in slot (u-y0+2)&3.
template <int K, bool EDGEY, bool DOLOAD>
__device__ __forceinline__ void step(Regs& R, int rr, int y0, int p0,
        const float* __restrict__ i1, const float* __restrict__ i2) {
    constexpr int Sm1 = (K + 2) & 3;   // row r-1 (freed by vs; load target r+3)
    constexpr int S0  = (K + 3) & 3;   // row r (center)
    constexpr int Sp1 =  K;            // row r+1
    constexpr int Sp2 = (K + 1) & 3;   // row r+2
    const int r = y0 - 1 + rr;

    // vertical 4-sums at own 2 cols (consumes oldest slot)
    const float vs1_0 = (R.ra[Sm1][0] + R.ra[S0][0]) + (R.ra[Sp1][0] + R.ra[Sp2][0]);
    const float vs1_1 = (R.ra[Sm1][1] + R.ra[S0][1]) + (R.ra[Sp1][1] + R.ra[Sp2][1]);
    const float vs2_0 = (R.rb[Sm1][0] + R.rb[S0][0]) + (R.rb[Sp1][0] + R.rb[Sp2][0]);
    const float vs2_1 = (R.rb[Sm1][1] + R.rb[S0][1]) + (R.rb[Sp1][1] + R.rb[Sp2][1]);

    // halo shuffles round 1: vs at cols p0-1 (left lane) and p0+2,p0+3 (right)
    const float vL1  = up1(vs1_1), vL2  = up1(vs2_1);
    const float vR10 = dn1(vs1_0), vR11 = dn1(vs1_1);
    const float vR20 = dn1(vs2_0), vR21 = dn1(vs2_1);

    // prefetch row r+3 into freed slot; first consumed next step's vs
    if (DOLOAD)
        ld_row<Sm1, EDGEY>(R, i1, i2, y0 + 2 + rr, p0);

    // mu over cols [c-1, c+2]
    const float mu1_0 = ((vL1 + vs1_0) + (vs1_1 + vR10)) * 0.0625f;
    const float mu1_1 = ((vs1_0 + vs1_1) + (vR10 + vR11)) * 0.0625f;
    const float mu2_0 = ((vL2 + vs2_0) + (vs2_1 + vR20)) * 0.0625f;
    const float mu2_1 = ((vs2_0 + vs2_1) + (vR20 + vR21)) * 0.0625f;

    float msk = R.mc;
    if (EDGEY) msk *= (((unsigned)r < (unsigned)HH) ? 1.f : 0.f);

    const float c1_0 = (R.ra[S0][0] - mu1_0) * msk;
    const float c1_1 = (R.ra[S0][1] - mu1_1) * msk;
    const float c2_0 = (R.rb[S0][0] - mu2_0) * msk;
    const float c2_1 = (R.rb[S0][1] - mu2_1) * msk;

    // halo shuffles round 2: centered values at cols p0-1, p0+2, p0+3
    const float cL1  = up1(c1_1), cL2  = up1(c2_1);
    const float cR10 = dn1(c1_0), cR11 = dn1(c1_1);
    const float cR20 = dn1(c2_0), cR21 = dn1(c2_1);

    // products (own + halo, computed locally)
    const float pii0 = c1_0 * c1_0, pjj0 = c2_0 * c2_0, pij0 = c1_0 * c2_0;
    const float pii1 = c1_1 * c1_1, pjj1 = c2_1 * c2_1, pij1 = c1_1 * c2_1;
    const float pLii = cL1 * cL1,  pLjj = cL2 * cL2,  pLij = cL1 * cL2;
    const float pR0ii = cR10 * cR10, pR0jj = cR20 * cR20, pR0ij = cR10 * cR20;
    const float pR1ii = cR11 * cR11, pR1jj = cR21 * cR21, pR1ij = cR11 * cR21;

    // horizontal 4-sums over cols [o-1, o+2] -> H ring slot K
    {
        const float s = pii0 + pii1;
        R.Hii[K][0] = (pLii + s) + pR0ii;
        R.Hii[K][1] = (s + pR0ii) + pR1ii;
    }
    {
        const float s = pjj0 + pjj1;
        R.Hjj[K][0] = (pLjj + s) + pR0jj;
        R.Hjj[K][1] = (s + pR0jj) + pR1jj;
    }
    {
        const float s = pij0 + pij1;
        R.Hij[K][0] = (pLij + s) + pR0ij;
        R.Hij[K][1] = (s + pR0ij) + pR1ij;
    }

    // emit output row i = r-2 once H ring holds c-rows i-1..i+2
    if (rr >= 3) {
#pragma unroll
        for (int q = 0; q < 2; ++q) {
            float sii = (R.Hii[0][q] + R.Hii[1][q]) + (R.Hii[2][q] + R.Hii[3][q]);
            float sjj = (R.Hjj[0][q] + R.Hjj[1][q]) + (R.Hjj[2][q] + R.Hjj[3][q]);
            float sij = (R.Hij[0][q] + R.Hij[1][q]) + (R.Hij[2][q] + R.Hij[3][q]);
            sii = fmaxf(sii, EPf);
            sjj = fmaxf(sjj, EPf);
            const float pr = fmaxf(sii * sjj, 1e-35f);  // denormal-flush guard
            float L = sij * __builtin_amdgcn_rsqf(pr);
            L = fmaxf(L, -1.f);
            R.acc += R.ownf * (1.f - L);
        }
    }
}

template <bool EDGEY>
__device__ float run_tile(const float* __restrict__ i1, const float* __restrict__ i2,
                          int y0, int p0, float mc, float ownf) {
    Regs R;
    R.mc = mc; R.ownf = ownf; R.acc = 0.f;

    // prime ring: rows y0-2..y0+1 -> slots 2,3,0,1  (slot = (row-y0+2)&3)
    ld_row<2, EDGEY>(R, i1, i2, y0 - 2, p0);
    ld_row<3, EDGEY>(R, i1, i2, y0 - 1, p0);
    ld_row<0, EDGEY>(R, i1, i2, y0,     p0);
    ld_row<1, EDGEY>(R, i1, i2, y0 + 1, p0);

    // steps rr = 0..RY+2 (c-rows y0-1..y0+RY+1); step rr loads row y0+2+rr,
    // needed through row y0+RY+3 -> last load at rr = RY+1.
#pragma unroll 1
    for (int o = 0; o < RY / 4; ++o) {
        const int rrb = o * 4;
        step<0, EDGEY, true>(R, rrb + 0, y0, p0, i1, i2);
        step<1, EDGEY, true>(R, rrb + 1, y0, p0, i1, i2);
        step<2, EDGEY, true>(R, rrb + 2, y0, p0, i1, i2);
        step<3, EDGEY, true>(R, rrb + 3, y0, p0, i1, i2);
    }
    step<0, EDGEY, true >(R, RY + 0, y0, p0, i1, i2);
    step<1, EDGEY, true >(R, RY + 1, y0, p0, i1, i2);
    step<2, EDGEY, false>(R, RY + 2, y0, p0, i1, i2);

    return R.acc;
}

__global__ __launch_bounds__(256) void xcorr_loss_kernel(
        const float* __restrict__ img1, const float* __restrict__ img2,
        double* __restrict__ ws) {
    const int tid  = threadIdx.x;
    const int lane = tid & 63;
    const int wv   = tid >> 6;
    const int WX0  = (blockIdx.x * WPB + wv) * WOWN;
    const int p0   = WX0 - 4 + 2 * lane;        // own cols p0, p0+1 (p0 even)
    const int y0   = blockIdx.y * RY;

    const float mc   = ((unsigned)p0 < (unsigned)WW) ? 1.f : 0.f;
    const float ownf = (lane >= 2 && lane <= 61 && (unsigned)p0 < (unsigned)WW)
                       ? 1.f : 0.f;

    float acc;
    if (blockIdx.y == 0 || blockIdx.y == gridDim.y - 1)
        acc = run_tile<true >(img1, img2, y0, p0, mc, ownf);
    else
        acc = run_tile<false>(img1, img2, y0, p0, mc, ownf);

    // wave reduction -> LDS -> one double atomic per block
    float wsum = acc;
#pragma unroll
    for (int off = 32; off > 0; off >>= 1)
        wsum += __shfl_down(wsum, off, 64);

    __shared__ float wpart[WPB];
    if (lane == 0) wpart[wv] = wsum;
    __syncthreads();
    if (tid == 0)
        atomicAdd(ws, (double)((wpart[0] + wpart[1]) + (wpart[2] + wpart[3])));
}

__global__ void finalize_kernel(const double* __restrict__ ws, float* __restrict__ out) {
    double mean = ws[0] / ((double)HH * (double)WW);
    out[0] = (float)mean;
    out[1] = (float)mean;
}

extern "C" void kernel_launch(void* const* d_in, const int* in_sizes, int n_in,
                              void* d_out, int out_size, void* d_ws, size_t ws_size,
                              hipStream_t stream) {
    const float* img1 = (const float*)d_in[0];  // outputs
    const float* img2 = (const float*)d_in[1];  // labels
    double* ws = (double*)d_ws;

    hipMemsetAsync(d_ws, 0, sizeof(double), stream);

    dim3 grid(NXB, HH / RY);   // (9, 128) = 1152 blocks
    xcorr_loss_kernel<<<grid, dim3(256), 0, stream>>>(img1, img2, ws);
    finalize_kernel<<<1, 1, 0, stream>>>(ws, (float*)d_out);
}

// Round 8
// 160.342 us; speedup vs baseline: 1.5625x; 1.1248x over previous
//
#include <hip/hip_runtime.h>

// StructuralLoss: windowed ZNCC, sigma=4 -> w=2 (4x4 box windows).
//
// Structure history: R2 reg-ring 86us; R5/R6 LDS-exchange + barriers
// 140/101us (barrier-coupled); R7 wave-local shuffle exchange, no barriers,
// VGPR=52, 77us. R7 counters (VALU 32%, Occ 26.5%) exposed SCHEDULE
// quantization: 1152 blocks = 4.5 blocks/CU vs residency cap 4 (VGPR 52
// -> 4 waves/SIMD). Identical-duration blocks round-synchronize:
// 2 rounds for 1.125 rounds of work => ~44% of runtime at ~1/8 residency.
// Measured occupancy (16+2)/2 ~= 9/CU = 28% matches.
//
// R8: ONE change -- the decomposition. RY 32 -> 37, grid (9, 111) = 999
// blocks <= 1024 = cap. Every block resident from t=0: single round, no
// tail. Bottom overhang rows (4070-4106 in last tile row) masked by the
// existing EDGEY path + a wave-uniform emit-row guard (i < HH) -- the only
// code change inside step. Per-wave structure identical to R7 (VGPR 52;
// the 4-waves/SIMD cliff at 64 is the tripwire to watch).
//
// At full residency the 1-step-ahead prefetch spans ~4x375 ~= 1500 wall
// cycles > ~900 HBM latency -> covered without deepening the ring.

#define HH 4096
#define WW 4096
constexpr int RY   = 37;             // output rows per tile (37*111 = 4107 >= 4096)
constexpr int NYB  = 111;            // y tiles
constexpr int WOWN = 120;            // owned cols per wave
constexpr int WPB  = 4;              // waves per block
constexpr int NXB  = 9;              // x blocks (9*4*120 = 4320 >= 4096)
constexpr float EPf = 1e-20f;

__device__ __forceinline__ float up1(float v) { return __shfl_up(v, 1, 64); }
__device__ __forceinline__ float dn1(float v) { return __shfl_down(v, 1, 64); }

struct Regs {
    float ra[4][2], rb[4][2];               // raw ring: 4 rows x 2 cols x 2 imgs
    float Hii[4][2], Hjj[4][2], Hij[4][2];  // H ring per c-row
    float mc;                               // col-pair validity (image pad)
    float ownf;                             // ownership mask for emit
    float acc;
};

template <int SLOT, bool EDGEY>
__device__ __forceinline__ void ld_row(Regs& R,
        const float* __restrict__ i1, const float* __restrict__ i2,
        int t, int p0) {
    bool ok = ((unsigned)p0 < (unsigned)WW);
    if (EDGEY) ok = ok && ((unsigned)t < (unsigned)HH);
    float2 va = make_float2(0.f, 0.f), vb = make_float2(0.f, 0.f);
    if (ok) {
        const size_t off = (size_t)t * WW + (unsigned)p0;
        va = *(const float2*)(i1 + off);
        vb = *(const float2*)(i2 + off);
    }
    R.ra[SLOT][0] = va.x; R.ra[SLOT][1] = va.y;
    R.rb[SLOT][0] = vb.x; R.rb[SLOT][1] = vb.y;
}

// Step rr (c-row r = y0-1+rr), K = rr & 3. Row u lives in slot (u-y0)&3.
template <int K, bool EDGEY, bool DOLOAD>
__device__ __forceinline__ void step(Regs& R, int rr, int y0, int p0,
        const float* __restrict__ i1, const float* __restrict__ i2) {
    constexpr int Sm1 = (K + 2) & 3;   // row r-1 (freed by vs; load target r+3)
    constexpr int S0  = (K + 3) & 3;   // row r (center)
    constexpr int Sp1 =  K;            // row r+1
    constexpr int Sp2 = (K + 1) & 3;   // row r+2
    const int r = y0 - 1 + rr;

    // vertical 4-sums at own 2 cols (consumes oldest slot)
    const float vs1_0 = (R.ra[Sm1][0] + R.ra[S0][0]) + (R.ra[Sp1][0] + R.ra[Sp2][0]);
    const float vs1_1 = (R.ra[Sm1][1] + R.ra[S0][1]) + (R.ra[Sp1][1] + R.ra[Sp2][1]);
    const float vs2_0 = (R.rb[Sm1][0] + R.rb[S0][0]) + (R.rb[Sp1][0] + R.rb[Sp2][0]);
    const float vs2_1 = (R.rb[Sm1][1] + R.rb[S0][1]) + (R.rb[Sp1][1] + R.rb[Sp2][1]);

    // halo shuffles round 1: vs at cols p0-1 (left lane) and p0+2,p0+3 (right)
    const float vL1  = up1(vs1_1), vL2  = up1(vs2_1);
    const float vR10 = dn1(vs1_0), vR11 = dn1(vs1_1);
    const float vR20 = dn1(vs2_0), vR21 = dn1(vs2_1);

    // prefetch row r+3 into freed slot; first consumed next step's vs
    if (DOLOAD)
        ld_row<Sm1, EDGEY>(R, i1, i2, y0 + 2 + rr, p0);

    // mu over cols [c-1, c+2]
    const float mu1_0 = ((vL1 + vs1_0) + (vs1_1 + vR10)) * 0.0625f;
    const float mu1_1 = ((vs1_0 + vs1_1) + (vR10 + vR11)) * 0.0625f;
    const float mu2_0 = ((vL2 + vs2_0) + (vs2_1 + vR20)) * 0.0625f;
    const float mu2_1 = ((vs2_0 + vs2_1) + (vR20 + vR21)) * 0.0625f;

    float msk = R.mc;
    if (EDGEY) msk *= (((unsigned)r < (unsigned)HH) ? 1.f : 0.f);

    const float c1_0 = (R.ra[S0][0] - mu1_0) * msk;
    const float c1_1 = (R.ra[S0][1] - mu1_1) * msk;
    const float c2_0 = (R.rb[S0][0] - mu2_0) * msk;
    const float c2_1 = (R.rb[S0][1] - mu2_1) * msk;

    // halo shuffles round 2: centered values at cols p0-1, p0+2, p0+3
    const float cL1  = up1(c1_1), cL2  = up1(c2_1);
    const float cR10 = dn1(c1_0), cR11 = dn1(c1_1);
    const float cR20 = dn1(c2_0), cR21 = dn1(c2_1);

    // products (own + halo, computed locally)
    const float pii0 = c1_0 * c1_0, pjj0 = c2_0 * c2_0, pij0 = c1_0 * c2_0;
    const float pii1 = c1_1 * c1_1, pjj1 = c2_1 * c2_1, pij1 = c1_1 * c2_1;
    const float pLii = cL1 * cL1,  pLjj = cL2 * cL2,  pLij = cL1 * cL2;
    const float pR0ii = cR10 * cR10, pR0jj = cR20 * cR20, pR0ij = cR10 * cR20;
    const float pR1ii = cR11 * cR11, pR1jj = cR21 * cR21, pR1ij = cR11 * cR21;

    // horizontal 4-sums over cols [o-1, o+2] -> H ring slot K
    {
        const float s = pii0 + pii1;
        R.Hii[K][0] = (pLii + s) + pR0ii;
        R.Hii[K][1] = (s + pR0ii) + pR1ii;
    }
    {
        const float s = pjj0 + pjj1;
        R.Hjj[K][0] = (pLjj + s) + pR0jj;
        R.Hjj[K][1] = (s + pR0jj) + pR1jj;
    }
    {
        const float s = pij0 + pij1;
        R.Hij[K][0] = (pLij + s) + pR0ij;
        R.Hij[K][1] = (s + pR0ij) + pR1ij;
    }

    // emit output row i = r-2 once H ring holds c-rows i-1..i+2.
    // EDGEY bottom-overhang tiles: skip rows i >= HH (wave-uniform guard).
    if (rr >= 3 && (!EDGEY || (r - 2 < HH))) {
#pragma unroll
        for (int q = 0; q < 2; ++q) {
            float sii = (R.Hii[0][q] + R.Hii[1][q]) + (R.Hii[2][q] + R.Hii[3][q]);
            float sjj = (R.Hjj[0][q] + R.Hjj[1][q]) + (R.Hjj[2][q] + R.Hjj[3][q]);
            float sij = (R.Hij[0][q] + R.Hij[1][q]) + (R.Hij[2][q] + R.Hij[3][q]);
            sii = fmaxf(sii, EPf);
            sjj = fmaxf(sjj, EPf);
            const float pr = fmaxf(sii * sjj, 1e-35f);  // denormal-flush guard
            float L = sij * __builtin_amdgcn_rsqf(pr);
            L = fmaxf(L, -1.f);
            R.acc += R.ownf * (1.f - L);
        }
    }
}

template <bool EDGEY>
__device__ float run_tile(const float* __restrict__ i1, const float* __restrict__ i2,
                          int y0, int p0, float mc, float ownf) {
    Regs R;
    R.mc = mc; R.ownf = ownf; R.acc = 0.f;

    // prime ring: rows y0-2..y0+1 -> slots 2,3,0,1  (slot = (row-y0)&3)
    ld_row<2, EDGEY>(R, i1, i2, y0 - 2, p0);
    ld_row<3, EDGEY>(R, i1, i2, y0 - 1, p0);
    ld_row<0, EDGEY>(R, i1, i2, y0,     p0);
    ld_row<1, EDGEY>(R, i1, i2, y0 + 1, p0);

    // steps rr = 0..RY+2 = 0..39 (40 = 10x4); step rr loads row y0+2+rr,
    // needed through row y0+RY+3 -> last load at rr = RY+1 = 38.
#pragma unroll 1
    for (int o = 0; o < 9; ++o) {
        const int rrb = o * 4;
        step<0, EDGEY, true>(R, rrb + 0, y0, p0, i1, i2);
        step<1, EDGEY, true>(R, rrb + 1, y0, p0, i1, i2);
        step<2, EDGEY, true>(R, rrb + 2, y0, p0, i1, i2);
        step<3, EDGEY, true>(R, rrb + 3, y0, p0, i1, i2);
    }
    step<0, EDGEY, true >(R, 36, y0, p0, i1, i2);
    step<1, EDGEY, true >(R, 37, y0, p0, i1, i2);
    step<2, EDGEY, true >(R, 38, y0, p0, i1, i2);
    step<3, EDGEY, false>(R, 39, y0, p0, i1, i2);

    return R.acc;
}

__global__ __launch_bounds__(256) void xcorr_loss_kernel(
        const float* __restrict__ img1, const float* __restrict__ img2,
        double* __restrict__ ws) {
    const int tid  = threadIdx.x;
    const int lane = tid & 63;
    const int wv   = tid >> 6;
    const int WX0  = (blockIdx.x * WPB + wv) * WOWN;
    const int p0   = WX0 - 4 + 2 * lane;        // own cols p0, p0+1 (p0 even)
    const int y0   = blockIdx.y * RY;

    const float mc   = ((unsigned)p0 < (unsigned)WW) ? 1.f : 0.f;
    const float ownf = (lane >= 2 && lane <= 61 && (unsigned)p0 < (unsigned)WW)
                       ? 1.f : 0.f;

    float acc;
    if (blockIdx.y == 0 || blockIdx.y == gridDim.y - 1)
        acc = run_tile<true >(img1, img2, y0, p0, mc, ownf);
    else
        acc = run_tile<false>(img1, img2, y0, p0, mc, ownf);

    // wave reduction -> LDS -> one double atomic per block
    float wsum = acc;
#pragma unroll
    for (int off = 32; off > 0; off >>= 1)
        wsum += __shfl_down(wsum, off, 64);

    __shared__ float wpart[WPB];
    if (lane == 0) wpart[wv] = wsum;
    __syncthreads();
    if (tid == 0)
        atomicAdd(ws, (double)((wpart[0] + wpart[1]) + (wpart[2] + wpart[3])));
}

__global__ void finalize_kernel(const double* __restrict__ ws, float* __restrict__ out) {
    double mean = ws[0] / ((double)HH * (double)WW);
    out[0] = (float)mean;
    out[1] = (float)mean;
}

extern "C" void kernel_launch(void* const* d_in, const int* in_sizes, int n_in,
                              void* d_out, int out_size, void* d_ws, size_t ws_size,
                              hipStream_t stream) {
    const float* img1 = (const float*)d_in[0];  // outputs
    const float* img2 = (const float*)d_in[1];  // labels
    double* ws = (double*)d_ws;

    hipMemsetAsync(d_ws, 0, sizeof(double), stream);

    dim3 grid(NXB, NYB);   // (9, 111) = 999 blocks <= 1024 = residency cap
    xcorr_loss_kernel<<<grid, dim3(256), 0, stream>>>(img1, img2, ws);
    finalize_kernel<<<1, 1, 0, stream>>>(ws, (float*)d_out);
}